// Round 24
// baseline (174.173 us; speedup 1.0000x reference)
//
#include <hip/hip_runtime.h>
#include <hip/hip_bf16.h>

typedef short bf16x8 __attribute__((ext_vector_type(8)));
typedef float f32x4 __attribute__((ext_vector_type(4)));
typedef unsigned int u32x4 __attribute__((ext_vector_type(4)));

static __device__ __forceinline__ unsigned short f2bf(float f) {
  unsigned int u = __builtin_bit_cast(unsigned int, f);
  u += 0x7fffu + ((u >> 16) & 1u);
  return (unsigned short)(u >> 16);
}
static __device__ __forceinline__ float bf2f(unsigned short b) {
  unsigned int u = ((unsigned int)b) << 16;
  return __builtin_bit_cast(float, u);
}

// ============ fused0: proj + whs1 (+pmax1) only; mask moved into attn1 (fast loads) ============
__global__ __launch_bounds__(256) void fused0_kernel(
    const float* __restrict__ x, const float* __restrict__ Wp,
    const float* __restrict__ bp, const float* __restrict__ W1,
    const float* __restrict__ a1, unsigned short* __restrict__ WhT1,
    float* __restrict__ s_src1, float* __restrict__ s_dst1, float* __restrict__ pmax1) {
  __shared__ float xs[16][256];
  __shared__ float hsh[16][128];
  __shared__ float rsv[2][16][2];
  __shared__ float sdv[16];
  int tid = threadIdx.x;
  int b = blockIdx.x;
  int r0 = b * 16;
  int j = tid & 127, half = tid >> 7;
  for (int t = tid; t < 16 * 256; t += 256)
    xs[t >> 8][t & 255] = x[(size_t)(r0 + (t >> 8)) * 256 + (t & 255)];
  __syncthreads();
  {
    float acc[8];
#pragma unroll
    for (int r = 0; r < 8; ++r) acc[r] = 0.f;
    const float4* wp4 = reinterpret_cast<const float4*>(Wp + (size_t)j * 256);
#pragma unroll 4
    for (int k4 = 0; k4 < 64; ++k4) {
      float4 w = wp4[k4];
#pragma unroll
      for (int r = 0; r < 8; ++r) {
        float4 xv = *reinterpret_cast<const float4*>(&xs[half * 8 + r][k4 * 4]);
        acc[r] = fmaf(xv.x, w.x, acc[r]);
        acc[r] = fmaf(xv.y, w.y, acc[r]);
        acc[r] = fmaf(xv.z, w.z, acc[r]);
        acc[r] = fmaf(xv.w, w.w, acc[r]);
      }
    }
    float bb = bp[j];
#pragma unroll
    for (int r = 0; r < 8; ++r) {
      float v = acc[r] + bb;
      hsh[half * 8 + r][j] = v > 0.f ? v : 0.f;
    }
  }
  __syncthreads();
  {
    float acc2[8];
#pragma unroll
    for (int r = 0; r < 8; ++r) acc2[r] = 0.f;
    const float4* w14 = reinterpret_cast<const float4*>(W1 + (size_t)j * 128);
#pragma unroll 4
    for (int k4 = 0; k4 < 32; ++k4) {
      float4 w = w14[k4];
#pragma unroll
      for (int r = 0; r < 8; ++r) {
        float4 xv = *reinterpret_cast<const float4*>(&hsh[half * 8 + r][k4 * 4]);
        acc2[r] = fmaf(xv.x, w.x, acc2[r]);
        acc2[r] = fmaf(xv.y, w.y, acc2[r]);
        acc2[r] = fmaf(xv.z, w.z, acc2[r]);
        acc2[r] = fmaf(xv.w, w.w, acc2[r]);
      }
    }
    float asrc = a1[j], adst = a1[128 + j];
    int lane = tid & 63, wv = tid >> 6;
#pragma unroll
    for (int r = 0; r < 8; ++r) {
      int rr = r0 + half * 8 + r;
      WhT1[(size_t)(rr >> 5) * (128 * 32) + (size_t)j * 32 + (rr & 31)] = f2bf(acc2[r]);
      float vs = acc2[r] * asrc, vd = acc2[r] * adst;
#pragma unroll
      for (int off = 32; off; off >>= 1) {
        vs += __shfl_xor(vs, off);
        vd += __shfl_xor(vd, off);
      }
      if (lane == 0) { rsv[0][half * 8 + r][wv & 1] = vs; rsv[1][half * 8 + r][wv & 1] = vd; }
    }
    __syncthreads();
    if (tid < 16) {
      float vs = rsv[0][tid][0] + rsv[0][tid][1];
      float vd = rsv[1][tid][0] + rsv[1][tid][1];
      s_src1[r0 + tid] = vs;
      s_dst1[r0 + tid] = vd;
      sdv[tid] = vd;
    }
    __syncthreads();
    if (tid == 0) {
      float m = sdv[0];
#pragma unroll
      for (int i = 1; i < 16; ++i) m = fmaxf(m, sdv[i]);
      pmax1[b] = m;
    }
  }
}

// -------- standalone mask (fallback when S != 16): row-mapped ballot + NT --------
__global__ __launch_bounds__(256) void mask_kernel(const int* __restrict__ adj,
                                                   unsigned char* __restrict__ maskb) {
  int wid = blockIdx.x * 4 + (threadIdx.x >> 6);
  int lane = threadIdx.x & 63;
  const int* arow = adj + (size_t)wid * 8192;
  unsigned char* mrow = maskb + (size_t)wid * 1024;
#pragma unroll 2
  for (int it = 0; it < 16; ++it) {
    int cbase = it * 512;
    unsigned long long b0, b1, b2, b3, b4, b5, b6, b7;
    {
      int v;
      v = __builtin_nontemporal_load(arow + cbase + 0 * 64 + lane); b0 = __ballot(v > 0);
      v = __builtin_nontemporal_load(arow + cbase + 1 * 64 + lane); b1 = __ballot(v > 0);
      v = __builtin_nontemporal_load(arow + cbase + 2 * 64 + lane); b2 = __ballot(v > 0);
      v = __builtin_nontemporal_load(arow + cbase + 3 * 64 + lane); b3 = __ballot(v > 0);
      v = __builtin_nontemporal_load(arow + cbase + 4 * 64 + lane); b4 = __ballot(v > 0);
      v = __builtin_nontemporal_load(arow + cbase + 5 * 64 + lane); b5 = __ballot(v > 0);
      v = __builtin_nontemporal_load(arow + cbase + 6 * 64 + lane); b6 = __ballot(v > 0);
      v = __builtin_nontemporal_load(arow + cbase + 7 * 64 + lane); b7 = __ballot(v > 0);
    }
    int idx = lane >> 3;
    unsigned long long sel = b0;
    sel = (idx == 1) ? b1 : sel;
    sel = (idx == 2) ? b2 : sel;
    sel = (idx == 3) ? b3 : sel;
    sel = (idx == 4) ? b4 : sel;
    sel = (idx == 5) ? b5 : sel;
    sel = (idx == 6) ? b6 : sel;
    sel = (idx == 7) ? b7 : sel;
    mrow[(cbase >> 3) + lane] = (unsigned char)(sel >> ((lane & 7) * 8));
  }
}

// p = max(A*B, C*D) masked = exact softmax weight exp(lrelu(e)-m); pack pair->bf16 trunc
static __device__ __forceinline__ bf16x8 buildp(float Af, float Cf, float4 ba, float4 bb,
                                                float4 da, float4 db, unsigned int mb) {
  float bv[8] = {ba.x, ba.y, ba.z, ba.w, bb.x, bb.y, bb.z, bb.w};
  float dv[8] = {da.x, da.y, da.z, da.w, db.x, db.y, db.z, db.w};
  u32x4 pw;
#pragma unroll
  for (int q = 0; q < 4; ++q) {
    float plo = fmaxf(Af * bv[2 * q], Cf * dv[2 * q]);
    float phi = fmaxf(Af * bv[2 * q + 1], Cf * dv[2 * q + 1]);
    plo = ((mb >> (2 * q)) & 1u) ? plo : 0.f;
    phi = ((mb >> (2 * q + 1)) & 1u) ? phi : 0.f;
    pw[q] = __builtin_amdgcn_perm(__builtin_bit_cast(unsigned int, phi),
                                  __builtin_bit_cast(unsigned int, plo), 0x07060302u);
  }
  return __builtin_bit_cast(bf16x8, pw);
}

// ============ attn: 8-wave block, LDS WhT (padded 40) + LDS mask strip ============
// MASKGEN=true (layer 1, requires cps==512): block builds its 256x512 mask strip from adj
// in the prologue via BALLOT + NONTEMPORAL loads (the fast ~5TB/s pattern R21 measured —
// R16's neutral fusion used the slow int4-pair loads), writes bytes to global for attn2.
// MASKGEN=false (layer 2): chunked preload from global as before.
template <int F, bool MASKGEN>
__global__ __launch_bounds__(512, 4) void attn_kernel(
    const int* __restrict__ adj, const unsigned char* __restrict__ maskb_r,
    unsigned char* __restrict__ maskb_w, const float* __restrict__ s_src,
    const float* __restrict__ s_dst, const float* __restrict__ pmax, int npmax,
    const unsigned short* __restrict__ WhT, unsigned short* __restrict__ pacc,
    float* __restrict__ pl, int cps, int S) {
  constexpr int NP = F / 64;
  constexpr int RS = 40;
  __shared__ unsigned short lds[2][2 * F * RS];
  __shared__ int4 mskl4[256 * 5];
  __shared__ float Bl[2048], Dl[2048];
  __shared__ float2 ACl[256];
  __shared__ float red[8];
  int tid = threadIdx.x;
  int lane = tid & 63, wv = tid >> 6;
  int rsub = lane & 15, kg = lane >> 4;
  int r0b = blockIdx.x * 256;
  int r0 = r0b + wv * 32;
  int by = blockIdx.y;
  int cbeg = by * cps;
  int ntile = cps >> 6;
  const unsigned char* mskb = reinterpret_cast<const unsigned char*>(mskl4);
  unsigned char* mskw = reinterpret_cast<unsigned char*>(mskl4);

  int sdest[NP];
#pragma unroll
  for (int p = 0; p < NP; ++p) {
    int c = tid + p * 512;
    int ks = c / (F * 4), rem = c % (F * 4);
    sdest[p] = ks * (F * RS) + (rem >> 2) * RS + (rem & 3) * 8;
  }

  float pv = -1e30f;
  for (int i = tid; i < npmax; i += 512) pv = fmaxf(pv, pmax[i]);
#pragma unroll
  for (int off = 32; off; off >>= 1) pv = fmaxf(pv, __shfl_xor(pv, off));
  if (lane == 0) red[wv] = pv;
  __syncthreads();
  float g = red[0];
#pragma unroll
  for (int i = 1; i < 8; ++i) g = fmaxf(g, red[i]);
  for (int t = tid; t < cps; t += 512) {
    float sd = s_dst[cbeg + t] - g;
    Bl[t] = __expf(sd);
    Dl[t] = __expf(0.2f * sd);
  }
  if (tid < 256) {
    float e0 = s_src[r0b + tid] + g;
    ACl[tid] = make_float2(__expf(fminf(0.8f * e0, 0.f)), __expf(fminf(-0.8f * e0, 0.f)));
  }
  if (MASKGEN) {
    // each wave: 32 rows; per row 8 ballot+NT loads (256B contiguous each) -> 64B mask
#pragma unroll 2
    for (int r = 0; r < 32; ++r) {
      int rl = wv * 32 + r;
      int row = r0b + rl;
      const int* base = adj + (size_t)row * 8192 + cbeg;
      unsigned long long b0, b1, b2, b3, b4, b5, b6, b7;
      {
        int v;
        v = __builtin_nontemporal_load(base + 0 * 64 + lane); b0 = __ballot(v > 0);
        v = __builtin_nontemporal_load(base + 1 * 64 + lane); b1 = __ballot(v > 0);
        v = __builtin_nontemporal_load(base + 2 * 64 + lane); b2 = __ballot(v > 0);
        v = __builtin_nontemporal_load(base + 3 * 64 + lane); b3 = __ballot(v > 0);
        v = __builtin_nontemporal_load(base + 4 * 64 + lane); b4 = __ballot(v > 0);
        v = __builtin_nontemporal_load(base + 5 * 64 + lane); b5 = __ballot(v > 0);
        v = __builtin_nontemporal_load(base + 6 * 64 + lane); b6 = __ballot(v > 0);
        v = __builtin_nontemporal_load(base + 7 * 64 + lane); b7 = __ballot(v > 0);
      }
      int idx = lane >> 3;
      unsigned long long sel = b0;
      sel = (idx == 1) ? b1 : sel;
      sel = (idx == 2) ? b2 : sel;
      sel = (idx == 3) ? b3 : sel;
      sel = (idx == 4) ? b4 : sel;
      sel = (idx == 5) ? b5 : sel;
      sel = (idx == 6) ? b6 : sel;
      sel = (idx == 7) ? b7 : sel;
      unsigned char byte = (unsigned char)(sel >> ((lane & 7) * 8));
      mskw[rl * 80 + lane] = byte;
      maskb_w[(size_t)row * 1024 + (cbeg >> 3) + lane] = byte;
    }
  }
  const int4* gw = reinterpret_cast<const int4*>(WhT + (size_t)(cbeg >> 5) * (F * 32));
  {
    int4 s0[NP];
#pragma unroll
    for (int p = 0; p < NP; ++p) s0[p] = gw[tid + p * 512];
#pragma unroll
    for (int p = 0; p < NP; ++p)
      *reinterpret_cast<int4*>(&lds[0][sdest[p]]) = s0[p];
  }
  __syncthreads();

  float2 ac0 = ACl[wv * 32 + rsub], ac1 = ACl[wv * 32 + 16 + rsub];
  f32x4 acc0[F / 16], acc1[F / 16];
#pragma unroll
  for (int t = 0; t < F / 16; ++t) { acc0[t] = (f32x4)0.f; acc1[t] = (f32x4)0.f; }
  f32x4 accl0 = (f32x4)0.f, accl1 = (f32x4)0.f;
  bf16x8 ones;
#pragma unroll
  for (int jj = 0; jj < 8; ++jj) ones[jj] = (short)0x3F80;
  const int rowoff = rsub * RS + kg * 8;
  const int mrow0 = (wv * 32 + rsub) * 80, mrow1 = (wv * 32 + 16 + rsub) * 80;

  for (int tt = 0; tt < ntile; ++tt) {
    if (!MASKGEN && (tt & 7) == 0) {
      int moff = (cbeg >> 3) + tt * 8;
#pragma unroll
      for (int q = tid; q < 1024; q += 512) {
        int row = q >> 2, qq = q & 3;
        int4 mv = *reinterpret_cast<const int4*>(
            maskb_r + (size_t)(r0b + row) * 1024 + moff + qq * 16);
        mskl4[row * 5 + qq] = mv;
      }
      __syncthreads();
    }
    int bi = tt & 1;
    bool more = tt + 1 < ntile;
    int4 sg[NP];
    if (more) {
#pragma unroll
      for (int p = 0; p < NP; ++p) sg[p] = gw[(tt + 1) * (F * 8) + tid + p * 512];
    }
    int tmod = MASKGEN ? tt * 8 : (tt & 7) * 8;
    unsigned long long mv0 =
        *reinterpret_cast<const unsigned long long*>(mskb + mrow0 + tmod);
    unsigned long long mv1 =
        *reinterpret_cast<const unsigned long long*>(mskb + mrow1 + tmod);
    int cl = tt * 64 + kg * 8;
    __builtin_amdgcn_sched_barrier(0);
    {  // ks = 0
      const unsigned short* lbk = &lds[bi][0];
      bf16x8 bfrag[F / 16];
#pragma unroll
      for (int t = 0; t < F / 16; ++t)
        bfrag[t] = *reinterpret_cast<const bf16x8*>(lbk + t * (16 * RS) + rowoff);
      float4 bA0 = *reinterpret_cast<const float4*>(&Bl[cl]);
      float4 bA1 = *reinterpret_cast<const float4*>(&Bl[cl + 4]);
      float4 dA0 = *reinterpret_cast<const float4*>(&Dl[cl]);
      float4 dA1 = *reinterpret_cast<const float4*>(&Dl[cl + 4]);
      unsigned sh = kg * 8;
      bf16x8 af0 = buildp(ac0.x, ac0.y, bA0, bA1, dA0, dA1, (unsigned)(mv0 >> sh) & 0xffu);
      accl0 = __builtin_amdgcn_mfma_f32_16x16x32_bf16(af0, ones, accl0, 0, 0, 0);
#pragma unroll
      for (int t = 0; t < F / 16; ++t)
        acc0[t] = __builtin_amdgcn_mfma_f32_16x16x32_bf16(af0, bfrag[t], acc0[t], 0, 0, 0);
      bf16x8 af1 = buildp(ac1.x, ac1.y, bA0, bA1, dA0, dA1, (unsigned)(mv1 >> sh) & 0xffu);
      accl1 = __builtin_amdgcn_mfma_f32_16x16x32_bf16(af1, ones, accl1, 0, 0, 0);
#pragma unroll
      for (int t = 0; t < F / 16; ++t)
        acc1[t] = __builtin_amdgcn_mfma_f32_16x16x32_bf16(af1, bfrag[t], acc1[t], 0, 0, 0);
    }
    {  // ks = 1
      const unsigned short* lbk = &lds[bi][F * RS];
      bf16x8 bfrag[F / 16];
#pragma unroll
      for (int t = 0; t < F / 16; ++t)
        bfrag[t] = *reinterpret_cast<const bf16x8*>(lbk + t * (16 * RS) + rowoff);
      float4 bB0 = *reinterpret_cast<const float4*>(&Bl[cl + 32]);
      float4 bB1 = *reinterpret_cast<const float4*>(&Bl[cl + 36]);
      float4 dB0 = *reinterpret_cast<const float4*>(&Dl[cl + 32]);
      float4 dB1 = *reinterpret_cast<const float4*>(&Dl[cl + 36]);
      unsigned sh = 32 + kg * 8;
      bf16x8 af0 = buildp(ac0.x, ac0.y, bB0, bB1, dB0, dB1, (unsigned)(mv0 >> sh) & 0xffu);
      accl0 = __builtin_amdgcn_mfma_f32_16x16x32_bf16(af0, ones, accl0, 0, 0, 0);
#pragma unroll
      for (int t = 0; t < F / 16; ++t)
        acc0[t] = __builtin_amdgcn_mfma_f32_16x16x32_bf16(af0, bfrag[t], acc0[t], 0, 0, 0);
      bf16x8 af1 = buildp(ac1.x, ac1.y, bB0, bB1, dB0, dB1, (unsigned)(mv1 >> sh) & 0xffu);
      accl1 = __builtin_amdgcn_mfma_f32_16x16x32_bf16(af1, ones, accl1, 0, 0, 0);
#pragma unroll
      for (int t = 0; t < F / 16; ++t)
        acc1[t] = __builtin_amdgcn_mfma_f32_16x16x32_bf16(af1, bfrag[t], acc1[t], 0, 0, 0);
    }
    __builtin_amdgcn_sched_barrier(0);
    if (more) {
#pragma unroll
      for (int p = 0; p < NP; ++p)
        *reinterpret_cast<int4*>(&lds[bi ^ 1][sdest[p]]) = sg[p];
    }
    __syncthreads();
  }

  if (rsub == 0) {
#pragma unroll
    for (int q = 0; q < 4; ++q) {
      pl[(size_t)(r0 + kg * 4 + q) * S + by] = accl0[q];
      pl[(size_t)(r0 + 16 + kg * 4 + q) * S + by] = accl1[q];
    }
  }
#pragma unroll
  for (int t = 0; t < F / 16; ++t) {
    int col = t * 16 + rsub;
#pragma unroll
    for (int q = 0; q < 4; ++q) {
      pacc[((size_t)(r0 + kg * 4 + q) * S + by) * F + col] = f2bf(acc0[t][q]);
      pacc[((size_t)(r0 + 16 + kg * 4 + q) * S + by) * F + col] = f2bf(acc1[t][q]);
    }
  }
}

// ====== whs2e v2: 2048 blocks x 256 threads (4 rows/block, one wave per row) ======
__global__ __launch_bounds__(256) void whs2e_kernel(
    const unsigned short* __restrict__ pacc1, const float* __restrict__ pl1,
    const float* __restrict__ W2, const float* __restrict__ a2,
    unsigned short* __restrict__ WhT2, float* __restrict__ s_src2,
    float* __restrict__ s_dst2, float* __restrict__ pmax2, int S) {
  __shared__ float hsh[4][128];
  __shared__ float sdv[4];
  int tid = threadIdx.x;
  int c2 = tid & 63, q = tid >> 6;
  int rr = blockIdx.x * 4 + q;
  {
    float l = 0.f;
    for (int s = 0; s < S; ++s) l += pl1[(size_t)rr * S + s];
    float a0 = 0.f, a1v = 0.f;
    for (int s = 0; s < S; ++s) {
      unsigned u = *reinterpret_cast<const unsigned*>(
          pacc1 + ((size_t)rr * S + s) * 128 + c2 * 2);
      a0 += bf2f((unsigned short)(u & 0xffffu));
      a1v += bf2f((unsigned short)(u >> 16));
    }
    float v0 = a0 / l, v1 = a1v / l;
    v0 = v0 > 0.f ? v0 : expm1f(v0);
    v1 = v1 > 0.f ? v1 : expm1f(v1);
    hsh[q][c2 * 2] = v0;
    hsh[q][c2 * 2 + 1] = v1;
  }
  __syncthreads();
  float acc2 = 0.f;
  const float4* w24 = reinterpret_cast<const float4*>(W2 + (size_t)c2 * 128);
#pragma unroll 8
  for (int k4 = 0; k4 < 32; ++k4) {
    float4 w = w24[k4];
    float4 xv = *reinterpret_cast<const float4*>(&hsh[q][k4 * 4]);
    acc2 = fmaf(xv.x, w.x, acc2);
    acc2 = fmaf(xv.y, w.y, acc2);
    acc2 = fmaf(xv.z, w.z, acc2);
    acc2 = fmaf(xv.w, w.w, acc2);
  }
  WhT2[(size_t)(rr >> 5) * (64 * 32) + (size_t)c2 * 32 + (rr & 31)] = f2bf(acc2);
  float vs = acc2 * a2[c2], vd = acc2 * a2[64 + c2];
#pragma unroll
  for (int off = 32; off; off >>= 1) {
    vs += __shfl_xor(vs, off);
    vd += __shfl_xor(vd, off);
  }
  if (c2 == 0) {
    s_src2[rr] = vs;
    s_dst2[rr] = vd;
    sdv[q] = vd;
  }
  __syncthreads();
  if (tid == 0)
    pmax2[blockIdx.x] = fmaxf(fmaxf(sdv[0], sdv[1]), fmaxf(sdv[2], sdv[3]));
}

// -------- epi2: out = (sum_s pacc2) / (sum_s l), no ELU --------
__global__ void epi_kernel(const unsigned short* __restrict__ pacc,
                           const float* __restrict__ pl, float* __restrict__ out, int S) {
  int idx = blockIdx.x * 256 + threadIdx.x;
  int row = idx >> 6, c = idx & 63;
  float l = 0.f, a = 0.f;
  for (int s = 0; s < S; ++s) {
    l += pl[(size_t)row * S + s];
    a += bf2f(pacc[((size_t)row * S + s) * 64 + c]);
  }
  out[idx] = a / l;
}

extern "C" void kernel_launch(void* const* d_in, const int* in_sizes, int n_in,
                              void* d_out, int out_size, void* d_ws, size_t ws_size,
                              hipStream_t stream) {
  const float* x  = (const float*)d_in[0];
  const int* adj  = (const int*)d_in[1];
  const float* Wp = (const float*)d_in[2];
  const float* bp = (const float*)d_in[3];
  const float* W1 = (const float*)d_in[4];
  const float* a1 = (const float*)d_in[5];
  const float* W2 = (const float*)d_in[6];
  const float* a2 = (const float*)d_in[7];
  float* out = (float*)d_out;

  int S = 4;
  if (ws_size >= (18ull + 48) * 1024 * 1024) S = 16;
  else if (ws_size >= (18ull + 24) * 1024 * 1024) S = 8;
  int cps = 8192 / S;

  char* ws = (char*)d_ws;
  unsigned short* WhT1 = (unsigned short*)(ws + 0);
  unsigned short* WhT2 = (unsigned short*)(ws + (2ull << 20));
  char* sm = ws + (3ull << 20);
  float* s_src1 = (float*)(sm + 0 * 32768);
  float* s_dst1 = (float*)(sm + 1 * 32768);
  float* s_src2 = (float*)(sm + 2 * 32768);
  float* s_dst2 = (float*)(sm + 3 * 32768);
  float* pmax1  = (float*)(sm + 4 * 32768);
  float* pmax2  = (float*)(sm + 4 * 32768 + 16384);
  unsigned char* maskb = (unsigned char*)(ws + (8ull << 20));
  float* pl1    = (float*)(ws + (16ull << 20));
  float* pl2    = (float*)(ws + (17ull << 20));
  unsigned short* pacc1 = (unsigned short*)(ws + (18ull << 20));
  unsigned short* pacc2 = pacc1 + (size_t)S * 8192 * 128;

  fused0_kernel<<<512, 256, 0, stream>>>(x, Wp, bp, W1, a1, WhT1, s_src1, s_dst1, pmax1);
  if (S == 16) {
    // maskgen fused into attn1 (requires cps==512); adj streamed once, in-LDS masks
    attn_kernel<128, true><<<dim3(32, 16), 512, 0, stream>>>(
        adj, maskb, maskb, s_src1, s_dst1, pmax1, 512, WhT1, pacc1, pl1, cps, S);
  } else {
    mask_kernel<<<2048, 256, 0, stream>>>(adj, maskb);
    attn_kernel<128, false><<<dim3(32, S), 512, 0, stream>>>(
        adj, maskb, maskb, s_src1, s_dst1, pmax1, 512, WhT1, pacc1, pl1, cps, S);
  }
  whs2e_kernel<<<2048, 256, 0, stream>>>(pacc1, pl1, W2, a2, WhT2, s_src2, s_dst2,
                                         pmax2, S);
  attn_kernel<64, false><<<dim3(32, S), 512, 0, stream>>>(
      adj, maskb, maskb, s_src2, s_dst2, pmax2, 2048, WhT2, pacc2, pl2, cps, S);
  epi_kernel<<<2048, 256, 0, stream>>>(pacc2, pl2, out, S);
}

// Round 25
// 166.212 us; speedup vs baseline: 1.0479x; 1.0479x over previous
//
#include <hip/hip_runtime.h>
#include <hip/hip_bf16.h>

typedef short bf16x8 __attribute__((ext_vector_type(8)));
typedef float f32x4 __attribute__((ext_vector_type(4)));
typedef unsigned int u32x4 __attribute__((ext_vector_type(4)));

static __device__ __forceinline__ unsigned short f2bf(float f) {
  unsigned int u = __builtin_bit_cast(unsigned int, f);
  u += 0x7fffu + ((u >> 16) & 1u);
  return (unsigned short)(u >> 16);
}
static __device__ __forceinline__ float bf2f(unsigned short b) {
  unsigned int u = ((unsigned int)b) << 16;
  return __builtin_bit_cast(float, u);
}

// ============ fused0: blocks 0-511 proj+whs1 (+pmax1); blocks 512-2559 adj->mask ============
// (R23 best shape: mask as separate blocks overlapping proj via grid co-residency.)
__global__ __launch_bounds__(256) void fused0_kernel(
    const int* __restrict__ adj, unsigned char* __restrict__ maskb,
    const float* __restrict__ x, const float* __restrict__ Wp,
    const float* __restrict__ bp, const float* __restrict__ W1,
    const float* __restrict__ a1, unsigned short* __restrict__ WhT1,
    float* __restrict__ s_src1, float* __restrict__ s_dst1, float* __restrict__ pmax1) {
  __shared__ float xs[16][256];
  __shared__ float hsh[16][128];
  __shared__ float rsv[2][16][2];
  __shared__ float sdv[16];
  int tid = threadIdx.x;
  int b = blockIdx.x;
  if (b >= 512) {
    int wid = (b - 512) * 4 + (tid >> 6);
    int lane = tid & 63;
    const int* arow = adj + (size_t)wid * 8192;
    unsigned char* mrow = maskb + (size_t)wid * 1024;
#pragma unroll 2
    for (int it = 0; it < 16; ++it) {
      int cbase = it * 512;
      unsigned long long b0, b1, b2, b3, b4, b5, b6, b7;
      {
        int v;
        v = __builtin_nontemporal_load(arow + cbase + 0 * 64 + lane); b0 = __ballot(v > 0);
        v = __builtin_nontemporal_load(arow + cbase + 1 * 64 + lane); b1 = __ballot(v > 0);
        v = __builtin_nontemporal_load(arow + cbase + 2 * 64 + lane); b2 = __ballot(v > 0);
        v = __builtin_nontemporal_load(arow + cbase + 3 * 64 + lane); b3 = __ballot(v > 0);
        v = __builtin_nontemporal_load(arow + cbase + 4 * 64 + lane); b4 = __ballot(v > 0);
        v = __builtin_nontemporal_load(arow + cbase + 5 * 64 + lane); b5 = __ballot(v > 0);
        v = __builtin_nontemporal_load(arow + cbase + 6 * 64 + lane); b6 = __ballot(v > 0);
        v = __builtin_nontemporal_load(arow + cbase + 7 * 64 + lane); b7 = __ballot(v > 0);
      }
      int idx = lane >> 3;
      unsigned long long sel = b0;
      sel = (idx == 1) ? b1 : sel;
      sel = (idx == 2) ? b2 : sel;
      sel = (idx == 3) ? b3 : sel;
      sel = (idx == 4) ? b4 : sel;
      sel = (idx == 5) ? b5 : sel;
      sel = (idx == 6) ? b6 : sel;
      sel = (idx == 7) ? b7 : sel;
      mrow[(cbase >> 3) + lane] = (unsigned char)(sel >> ((lane & 7) * 8));
    }
    return;
  }
  int r0 = b * 16;
  int j = tid & 127, half = tid >> 7;
  for (int t = tid; t < 16 * 256; t += 256)
    xs[t >> 8][t & 255] = x[(size_t)(r0 + (t >> 8)) * 256 + (t & 255)];
  __syncthreads();
  {
    float acc[8];
#pragma unroll
    for (int r = 0; r < 8; ++r) acc[r] = 0.f;
    const float4* wp4 = reinterpret_cast<const float4*>(Wp + (size_t)j * 256);
#pragma unroll 4
    for (int k4 = 0; k4 < 64; ++k4) {
      float4 w = wp4[k4];
#pragma unroll
      for (int r = 0; r < 8; ++r) {
        float4 xv = *reinterpret_cast<const float4*>(&xs[half * 8 + r][k4 * 4]);
        acc[r] = fmaf(xv.x, w.x, acc[r]);
        acc[r] = fmaf(xv.y, w.y, acc[r]);
        acc[r] = fmaf(xv.z, w.z, acc[r]);
        acc[r] = fmaf(xv.w, w.w, acc[r]);
      }
    }
    float bb = bp[j];
#pragma unroll
    for (int r = 0; r < 8; ++r) {
      float v = acc[r] + bb;
      hsh[half * 8 + r][j] = v > 0.f ? v : 0.f;
    }
  }
  __syncthreads();
  {
    float acc2[8];
#pragma unroll
    for (int r = 0; r < 8; ++r) acc2[r] = 0.f;
    const float4* w14 = reinterpret_cast<const float4*>(W1 + (size_t)j * 128);
#pragma unroll 4
    for (int k4 = 0; k4 < 32; ++k4) {
      float4 w = w14[k4];
#pragma unroll
      for (int r = 0; r < 8; ++r) {
        float4 xv = *reinterpret_cast<const float4*>(&hsh[half * 8 + r][k4 * 4]);
        acc2[r] = fmaf(xv.x, w.x, acc2[r]);
        acc2[r] = fmaf(xv.y, w.y, acc2[r]);
        acc2[r] = fmaf(xv.z, w.z, acc2[r]);
        acc2[r] = fmaf(xv.w, w.w, acc2[r]);
      }
    }
    float asrc = a1[j], adst = a1[128 + j];
    int lane = tid & 63, wv = tid >> 6;
#pragma unroll
    for (int r = 0; r < 8; ++r) {
      int rr = r0 + half * 8 + r;
      WhT1[(size_t)(rr >> 5) * (128 * 32) + (size_t)j * 32 + (rr & 31)] = f2bf(acc2[r]);
      float vs = acc2[r] * asrc, vd = acc2[r] * adst;
#pragma unroll
      for (int off = 32; off; off >>= 1) {
        vs += __shfl_xor(vs, off);
        vd += __shfl_xor(vd, off);
      }
      if (lane == 0) { rsv[0][half * 8 + r][wv & 1] = vs; rsv[1][half * 8 + r][wv & 1] = vd; }
    }
    __syncthreads();
    if (tid < 16) {
      float vs = rsv[0][tid][0] + rsv[0][tid][1];
      float vd = rsv[1][tid][0] + rsv[1][tid][1];
      s_src1[r0 + tid] = vs;
      s_dst1[r0 + tid] = vd;
      sdv[tid] = vd;
    }
    __syncthreads();
    if (tid == 0) {
      float m = sdv[0];
#pragma unroll
      for (int i = 1; i < 16; ++i) m = fmaxf(m, sdv[i]);
      pmax1[b] = m;
    }
  }
}

// p = max(A*B, C*D) masked = exact softmax weight exp(lrelu(e)-m); pack pair->bf16 trunc
static __device__ __forceinline__ bf16x8 buildp(float Af, float Cf, float4 ba, float4 bb,
                                                float4 da, float4 db, unsigned int mb) {
  float bv[8] = {ba.x, ba.y, ba.z, ba.w, bb.x, bb.y, bb.z, bb.w};
  float dv[8] = {da.x, da.y, da.z, da.w, db.x, db.y, db.z, db.w};
  u32x4 pw;
#pragma unroll
  for (int q = 0; q < 4; ++q) {
    float plo = fmaxf(Af * bv[2 * q], Cf * dv[2 * q]);
    float phi = fmaxf(Af * bv[2 * q + 1], Cf * dv[2 * q + 1]);
    plo = ((mb >> (2 * q)) & 1u) ? plo : 0.f;
    phi = ((mb >> (2 * q + 1)) & 1u) ? phi : 0.f;
    pw[q] = __builtin_amdgcn_perm(__builtin_bit_cast(unsigned int, phi),
                                  __builtin_bit_cast(unsigned int, plo), 0x07060302u);
  }
  return __builtin_bit_cast(bf16x8, pw);
}

// ============ attn: 8-wave block, LDS WhT (padded 40) + LDS mask strip ============
template <int F>
__global__ __launch_bounds__(512, 4) void attn_kernel(
    const unsigned char* __restrict__ maskb, const float* __restrict__ s_src,
    const float* __restrict__ s_dst, const float* __restrict__ pmax, int npmax,
    const unsigned short* __restrict__ WhT, unsigned short* __restrict__ pacc,
    float* __restrict__ pl, int cps, int S) {
  constexpr int NP = F / 64;
  constexpr int RS = 40;
  __shared__ unsigned short lds[2][2 * F * RS];
  __shared__ int4 mskl4[256 * 5];
  __shared__ float Bl[2048], Dl[2048];
  __shared__ float2 ACl[256];
  __shared__ float red[8];
  int tid = threadIdx.x;
  int lane = tid & 63, wv = tid >> 6;
  int rsub = lane & 15, kg = lane >> 4;
  int r0b = blockIdx.x * 256;
  int r0 = r0b + wv * 32;
  int by = blockIdx.y;
  int cbeg = by * cps;
  int ntile = cps >> 6;
  const unsigned char* mskb = reinterpret_cast<const unsigned char*>(mskl4);

  int sdest[NP];
#pragma unroll
  for (int p = 0; p < NP; ++p) {
    int c = tid + p * 512;
    int ks = c / (F * 4), rem = c % (F * 4);
    sdest[p] = ks * (F * RS) + (rem >> 2) * RS + (rem & 3) * 8;
  }

  float pv = -1e30f;
  for (int i = tid; i < npmax; i += 512) pv = fmaxf(pv, pmax[i]);
#pragma unroll
  for (int off = 32; off; off >>= 1) pv = fmaxf(pv, __shfl_xor(pv, off));
  if (lane == 0) red[wv] = pv;
  __syncthreads();
  float g = red[0];
#pragma unroll
  for (int i = 1; i < 8; ++i) g = fmaxf(g, red[i]);
  for (int t = tid; t < cps; t += 512) {
    float sd = s_dst[cbeg + t] - g;
    Bl[t] = __expf(sd);
    Dl[t] = __expf(0.2f * sd);
  }
  if (tid < 256) {
    float e0 = s_src[r0b + tid] + g;
    ACl[tid] = make_float2(__expf(fminf(0.8f * e0, 0.f)), __expf(fminf(-0.8f * e0, 0.f)));
  }
  const int4* gw = reinterpret_cast<const int4*>(WhT + (size_t)(cbeg >> 5) * (F * 32));
  {
    int4 s0[NP];
#pragma unroll
    for (int p = 0; p < NP; ++p) s0[p] = gw[tid + p * 512];
#pragma unroll
    for (int p = 0; p < NP; ++p)
      *reinterpret_cast<int4*>(&lds[0][sdest[p]]) = s0[p];
  }
  __syncthreads();

  float2 ac0 = ACl[wv * 32 + rsub], ac1 = ACl[wv * 32 + 16 + rsub];
  f32x4 acc0[F / 16], acc1[F / 16];
#pragma unroll
  for (int t = 0; t < F / 16; ++t) { acc0[t] = (f32x4)0.f; acc1[t] = (f32x4)0.f; }
  f32x4 accl0 = (f32x4)0.f, accl1 = (f32x4)0.f;
  bf16x8 ones;
#pragma unroll
  for (int jj = 0; jj < 8; ++jj) ones[jj] = (short)0x3F80;
  const int rowoff = rsub * RS + kg * 8;
  const int mrow0 = (wv * 32 + rsub) * 80, mrow1 = (wv * 32 + 16 + rsub) * 80;

  for (int tt = 0; tt < ntile; ++tt) {
    if ((tt & 7) == 0) {
      int moff = (cbeg >> 3) + tt * 8;
#pragma unroll
      for (int q = tid; q < 1024; q += 512) {
        int row = q >> 2, qq = q & 3;
        int4 mv = *reinterpret_cast<const int4*>(
            maskb + (size_t)(r0b + row) * 1024 + moff + qq * 16);
        mskl4[row * 5 + qq] = mv;
      }
      __syncthreads();
    }
    int bi = tt & 1;
    bool more = tt + 1 < ntile;
    int4 sg[NP];
    if (more) {
#pragma unroll
      for (int p = 0; p < NP; ++p) sg[p] = gw[(tt + 1) * (F * 8) + tid + p * 512];
    }
    int tmod = (tt & 7) * 8;
    unsigned long long mv0 =
        *reinterpret_cast<const unsigned long long*>(mskb + mrow0 + tmod);
    unsigned long long mv1 =
        *reinterpret_cast<const unsigned long long*>(mskb + mrow1 + tmod);
    int cl = tt * 64 + kg * 8;
    __builtin_amdgcn_sched_barrier(0);
    {  // ks = 0
      const unsigned short* lbk = &lds[bi][0];
      bf16x8 bfrag[F / 16];
#pragma unroll
      for (int t = 0; t < F / 16; ++t)
        bfrag[t] = *reinterpret_cast<const bf16x8*>(lbk + t * (16 * RS) + rowoff);
      float4 bA0 = *reinterpret_cast<const float4*>(&Bl[cl]);
      float4 bA1 = *reinterpret_cast<const float4*>(&Bl[cl + 4]);
      float4 dA0 = *reinterpret_cast<const float4*>(&Dl[cl]);
      float4 dA1 = *reinterpret_cast<const float4*>(&Dl[cl + 4]);
      unsigned sh = kg * 8;
      bf16x8 af0 = buildp(ac0.x, ac0.y, bA0, bA1, dA0, dA1, (unsigned)(mv0 >> sh) & 0xffu);
      accl0 = __builtin_amdgcn_mfma_f32_16x16x32_bf16(af0, ones, accl0, 0, 0, 0);
#pragma unroll
      for (int t = 0; t < F / 16; ++t)
        acc0[t] = __builtin_amdgcn_mfma_f32_16x16x32_bf16(af0, bfrag[t], acc0[t], 0, 0, 0);
      bf16x8 af1 = buildp(ac1.x, ac1.y, bA0, bA1, dA0, dA1, (unsigned)(mv1 >> sh) & 0xffu);
      accl1 = __builtin_amdgcn_mfma_f32_16x16x32_bf16(af1, ones, accl1, 0, 0, 0);
#pragma unroll
      for (int t = 0; t < F / 16; ++t)
        acc1[t] = __builtin_amdgcn_mfma_f32_16x16x32_bf16(af1, bfrag[t], acc1[t], 0, 0, 0);
    }
    {  // ks = 1
      const unsigned short* lbk = &lds[bi][F * RS];
      bf16x8 bfrag[F / 16];
#pragma unroll
      for (int t = 0; t < F / 16; ++t)
        bfrag[t] = *reinterpret_cast<const bf16x8*>(lbk + t * (16 * RS) + rowoff);
      float4 bB0 = *reinterpret_cast<const float4*>(&Bl[cl + 32]);
      float4 bB1 = *reinterpret_cast<const float4*>(&Bl[cl + 36]);
      float4 dB0 = *reinterpret_cast<const float4*>(&Dl[cl + 32]);
      float4 dB1 = *reinterpret_cast<const float4*>(&Dl[cl + 36]);
      unsigned sh = 32 + kg * 8;
      bf16x8 af0 = buildp(ac0.x, ac0.y, bB0, bB1, dB0, dB1, (unsigned)(mv0 >> sh) & 0xffu);
      accl0 = __builtin_amdgcn_mfma_f32_16x16x32_bf16(af0, ones, accl0, 0, 0, 0);
#pragma unroll
      for (int t = 0; t < F / 16; ++t)
        acc0[t] = __builtin_amdgcn_mfma_f32_16x16x32_bf16(af0, bfrag[t], acc0[t], 0, 0, 0);
      bf16x8 af1 = buildp(ac1.x, ac1.y, bB0, bB1, dB0, dB1, (unsigned)(mv1 >> sh) & 0xffu);
      accl1 = __builtin_amdgcn_mfma_f32_16x16x32_bf16(af1, ones, accl1, 0, 0, 0);
#pragma unroll
      for (int t = 0; t < F / 16; ++t)
        acc1[t] = __builtin_amdgcn_mfma_f32_16x16x32_bf16(af1, bfrag[t], acc1[t], 0, 0, 0);
    }
    __builtin_amdgcn_sched_barrier(0);
    if (more) {
#pragma unroll
      for (int p = 0; p < NP; ++p)
        *reinterpret_cast<int4*>(&lds[bi ^ 1][sdest[p]]) = sg[p];
    }
    __syncthreads();
  }

  if (rsub == 0) {
#pragma unroll
    for (int q = 0; q < 4; ++q) {
      pl[(size_t)(r0 + kg * 4 + q) * S + by] = accl0[q];
      pl[(size_t)(r0 + 16 + kg * 4 + q) * S + by] = accl1[q];
    }
  }
#pragma unroll
  for (int t = 0; t < F / 16; ++t) {
    int col = t * 16 + rsub;
#pragma unroll
    for (int q = 0; q < 4; ++q) {
      pacc[((size_t)(r0 + kg * 4 + q) * S + by) * F + col] = f2bf(acc0[t][q]);
      pacc[((size_t)(r0 + 16 + kg * 4 + q) * S + by) * F + col] = f2bf(acc1[t][q]);
    }
  }
}

// ====== whs2e v3: 2048 blocks x 256 thr, 1 wave/row. S==16 fast path: 4x int4 loads
// cover the whole [16][128] bf16 slab (1KB/instruction vs v2's 256B), Σ_s via two
// shfl_xor(16,32); pl1 sum via broadcast load + 4-step xor reduce. ======
__global__ __launch_bounds__(256) void whs2e_kernel(
    const unsigned short* __restrict__ pacc1, const float* __restrict__ pl1,
    const float* __restrict__ W2, const float* __restrict__ a2,
    unsigned short* __restrict__ WhT2, float* __restrict__ s_src2,
    float* __restrict__ s_dst2, float* __restrict__ pmax2, int S) {
  __shared__ float hsh[4][128];
  __shared__ float sdv[4];
  int tid = threadIdx.x;
  int c2 = tid & 63, q = tid >> 6;
  int rr = blockIdx.x * 4 + q;
  int lane = c2;
  if (S == 16) {
    // ---- fast path: vectorized slab read ----
    float acc8[8];
#pragma unroll
    for (int j = 0; j < 8; ++j) acc8[j] = 0.f;
    const unsigned short* rowp = pacc1 + (size_t)rr * 2048;  // 16 s x 128 c shorts
#pragma unroll
    for (int i = 0; i < 4; ++i) {
      u32x4 v = *reinterpret_cast<const u32x4*>(rowp + (i * 64 + lane) * 8);
#pragma unroll
      for (int w = 0; w < 4; ++w) {
        acc8[2 * w] += bf2f((unsigned short)(v[w] & 0xffffu));
        acc8[2 * w + 1] += bf2f((unsigned short)(v[w] >> 16));
      }
    }
#pragma unroll
    for (int j = 0; j < 8; ++j) {
      acc8[j] += __shfl_xor(acc8[j], 16);
      acc8[j] += __shfl_xor(acc8[j], 32);
    }
    float lv = pl1[(size_t)rr * 16 + (lane & 15)];
    lv += __shfl_xor(lv, 1);
    lv += __shfl_xor(lv, 2);
    lv += __shfl_xor(lv, 4);
    lv += __shfl_xor(lv, 8);
    if (lane < 16) {
      int c0 = lane * 8;
#pragma unroll
      for (int j = 0; j < 8; ++j) {
        float v = acc8[j] / lv;
        hsh[q][c0 + j] = v > 0.f ? v : expm1f(v);
      }
    }
  } else {
    // ---- generic path (S = 4 or 8) ----
    float l = 0.f;
    for (int s = 0; s < S; ++s) l += pl1[(size_t)rr * S + s];
    float a0 = 0.f, a1v = 0.f;
    for (int s = 0; s < S; ++s) {
      unsigned u = *reinterpret_cast<const unsigned*>(
          pacc1 + ((size_t)rr * S + s) * 128 + c2 * 2);
      a0 += bf2f((unsigned short)(u & 0xffffu));
      a1v += bf2f((unsigned short)(u >> 16));
    }
    float v0 = a0 / l, v1 = a1v / l;
    v0 = v0 > 0.f ? v0 : expm1f(v0);
    v1 = v1 > 0.f ? v1 : expm1f(v1);
    hsh[q][c2 * 2] = v0;
    hsh[q][c2 * 2 + 1] = v1;
  }
  __syncthreads();
  float acc2 = 0.f;
  const float4* w24 = reinterpret_cast<const float4*>(W2 + (size_t)c2 * 128);
#pragma unroll 8
  for (int k4 = 0; k4 < 32; ++k4) {
    float4 w = w24[k4];
    float4 xv = *reinterpret_cast<const float4*>(&hsh[q][k4 * 4]);
    acc2 = fmaf(xv.x, w.x, acc2);
    acc2 = fmaf(xv.y, w.y, acc2);
    acc2 = fmaf(xv.z, w.z, acc2);
    acc2 = fmaf(xv.w, w.w, acc2);
  }
  WhT2[(size_t)(rr >> 5) * (64 * 32) + (size_t)c2 * 32 + (rr & 31)] = f2bf(acc2);
  float vs = acc2 * a2[c2], vd = acc2 * a2[64 + c2];
#pragma unroll
  for (int off = 32; off; off >>= 1) {
    vs += __shfl_xor(vs, off);
    vd += __shfl_xor(vd, off);
  }
  if (c2 == 0) {
    s_src2[rr] = vs;
    s_dst2[rr] = vd;
    sdv[q] = vd;
  }
  __syncthreads();
  if (tid == 0)
    pmax2[blockIdx.x] = fmaxf(fmaxf(sdv[0], sdv[1]), fmaxf(sdv[2], sdv[3]));
}

// -------- epi2: out = (sum_s pacc2) / (sum_s l), no ELU --------
__global__ void epi_kernel(const unsigned short* __restrict__ pacc,
                           const float* __restrict__ pl, float* __restrict__ out, int S) {
  int idx = blockIdx.x * 256 + threadIdx.x;
  int row = idx >> 6, c = idx & 63;
  float l = 0.f, a = 0.f;
  for (int s = 0; s < S; ++s) {
    l += pl[(size_t)row * S + s];
    a += bf2f(pacc[((size_t)row * S + s) * 64 + c]);
  }
  out[idx] = a / l;
}

extern "C" void kernel_launch(void* const* d_in, const int* in_sizes, int n_in,
                              void* d_out, int out_size, void* d_ws, size_t ws_size,
                              hipStream_t stream) {
  const float* x  = (const float*)d_in[0];
  const int* adj  = (const int*)d_in[1];
  const float* Wp = (const float*)d_in[2];
  const float* bp = (const float*)d_in[3];
  const float* W1 = (const float*)d_in[4];
  const float* a1 = (const float*)d_in[5];
  const float* W2 = (const float*)d_in[6];
  const float* a2 = (const float*)d_in[7];
  float* out = (float*)d_out;

  int S = 4;
  if (ws_size >= (18ull + 48) * 1024 * 1024) S = 16;
  else if (ws_size >= (18ull + 24) * 1024 * 1024) S = 8;
  int cps = 8192 / S;

  char* ws = (char*)d_ws;
  unsigned short* WhT1 = (unsigned short*)(ws + 0);
  unsigned short* WhT2 = (unsigned short*)(ws + (2ull << 20));
  char* sm = ws + (3ull << 20);
  float* s_src1 = (float*)(sm + 0 * 32768);
  float* s_dst1 = (float*)(sm + 1 * 32768);
  float* s_src2 = (float*)(sm + 2 * 32768);
  float* s_dst2 = (float*)(sm + 3 * 32768);
  float* pmax1  = (float*)(sm + 4 * 32768);
  float* pmax2  = (float*)(sm + 4 * 32768 + 16384);
  unsigned char* maskb = (unsigned char*)(ws + (8ull << 20));
  float* pl1    = (float*)(ws + (16ull << 20));
  float* pl2    = (float*)(ws + (17ull << 20));
  unsigned short* pacc1 = (unsigned short*)(ws + (18ull << 20));
  unsigned short* pacc2 = pacc1 + (size_t)S * 8192 * 128;

  fused0_kernel<<<2560, 256, 0, stream>>>(adj, maskb, x, Wp, bp, W1, a1, WhT1,
                                          s_src1, s_dst1, pmax1);
  attn_kernel<128><<<dim3(32, S), 512, 0, stream>>>(
      maskb, s_src1, s_dst1, pmax1, 512, WhT1, pacc1, pl1, cps, S);
  whs2e_kernel<<<2048, 256, 0, stream>>>(pacc1, pl1, W2, a2, WhT2, s_src2, s_dst2,
                                         pmax2, S);
  attn_kernel<64><<<dim3(32, S), 512, 0, stream>>>(
      maskb, s_src2, s_dst2, pmax2, 2048, WhT2, pacc2, pl2, cps, S);
  epi_kernel<<<2048, 256, 0, stream>>>(pacc2, pl2, out, S);
}